// Round 4
// baseline (223.441 us; speedup 1.0000x reference)
//
#include <hip/hip_runtime.h>
#include <hip/hip_bf16.h>
#include <stdint.h>

// Problem constants
#define BB 8
#define SS 1024
#define DD 512
#define MROWS (BB*SS)        // 8192
#define NEG_EPS 1e-9f
#define INV_S (1.0f/1024.0f)

typedef __attribute__((ext_vector_type(8))) __bf16 bf16x8;
typedef __attribute__((ext_vector_type(4))) __bf16 bf16x4;
typedef __attribute__((ext_vector_type(4))) float f32x4;

__device__ __forceinline__ void gload_lds16(const void* g, void* l) {
    __builtin_amdgcn_global_load_lds(
        (const __attribute__((address_space(1))) void*)g,
        (__attribute__((address_space(3))) void*)l,
        16, 0, 0);
}

// ============ K1: ctx->bf16 convert + M = Wq^T @ Wk (bf16) + bias vectors ============
// grid: [0,2048) convert, [2048,2304) M tiles, [2304,2320) bias vecs, 2320 c0
__global__ __launch_bounds__(256) void prep_all(const float* __restrict__ ctx,
                                                const float* __restrict__ Wq,
                                                const float* __restrict__ Wk,
                                                const float* __restrict__ bq,
                                                const float* __restrict__ bk,
                                                __bf16* __restrict__ ctx_bf,
                                                __bf16* __restrict__ m_bf,
                                                float* __restrict__ avec,
                                                float* __restrict__ bvec,
                                                float* __restrict__ c0p) {
    __shared__ float sQ[64 * 32];
    __shared__ float sK[64 * 32];
    __shared__ float red[256];
    __shared__ float sA[8][32];
    __shared__ float sB[8][32];
    const int blk = blockIdx.x;
    const int t = threadIdx.x;

    if (blk < 2048) {
        int i = (blk * 256 + t) * 4;
        const int stride = 2048 * 256 * 4;
        for (; i < MROWS * DD; i += stride) {
            f32x4 v = *(const f32x4*)(ctx + i);
            bf16x4 o;
            o[0] = (__bf16)v[0]; o[1] = (__bf16)v[1];
            o[2] = (__bf16)v[2]; o[3] = (__bf16)v[3];
            *(bf16x4*)(ctx_bf + i) = o;
        }
    } else if (blk < 2304) {
        // M[i,j] = sum_e Wq[e,i] * Wk[e,j]
        const int mb = blk - 2048;
        const int bi = mb >> 4, bj = mb & 15;
        const int ti = t >> 4, tj = t & 15;
        float acc00 = 0.f, acc01 = 0.f, acc10 = 0.f, acc11 = 0.f;
        for (int e0 = 0; e0 < 512; e0 += 64) {
            const int r = t >> 2, c8 = (t & 3) * 8;
            #pragma unroll
            for (int u = 0; u < 2; ++u) {
                f32x4 vq = *(const f32x4*)(Wq + (size_t)(e0 + r) * 512 + bi * 32 + c8 + u * 4);
                f32x4 vk = *(const f32x4*)(Wk + (size_t)(e0 + r) * 512 + bj * 32 + c8 + u * 4);
                *(f32x4*)(sQ + r * 32 + c8 + u * 4) = vq;
                *(f32x4*)(sK + r * 32 + c8 + u * 4) = vk;
            }
            __syncthreads();
            #pragma unroll 8
            for (int e = 0; e < 64; ++e) {
                float q0 = sQ[e * 32 + ti * 2], q1 = sQ[e * 32 + ti * 2 + 1];
                float k0 = sK[e * 32 + tj * 2], k1 = sK[e * 32 + tj * 2 + 1];
                acc00 += q0 * k0; acc01 += q0 * k1;
                acc10 += q1 * k0; acc11 += q1 * k1;
            }
            __syncthreads();
        }
        const int i0 = bi * 32 + ti * 2, j0 = bj * 32 + tj * 2;
        m_bf[(size_t)i0 * 512 + j0]           = (__bf16)acc00;
        m_bf[(size_t)i0 * 512 + j0 + 1]       = (__bf16)acc01;
        m_bf[(size_t)(i0 + 1) * 512 + j0]     = (__bf16)acc10;
        m_bf[(size_t)(i0 + 1) * 512 + j0 + 1] = (__bf16)acc11;
    } else if (blk < 2320) {
        // a = Wq^T bk, b = Wk^T bq — 16 blocks x 32 columns, 8 e-groups each
        const int bb = blk - 2304;
        const int d  = (t & 31) + bb * 32;
        const int eg = t >> 5;
        float a = 0.f, bv = 0.f;
        for (int e = eg * 64; e < eg * 64 + 64; ++e) {
            a  += Wq[(size_t)e * 512 + d] * bk[e];
            bv += Wk[(size_t)e * 512 + d] * bq[e];
        }
        sA[eg][t & 31] = a; sB[eg][t & 31] = bv;
        __syncthreads();
        if (t < 32) {
            float sa = 0.f, sb = 0.f;
            #pragma unroll
            for (int g = 0; g < 8; ++g) { sa += sA[g][t]; sb += sB[g][t]; }
            avec[bb * 32 + t] = sa; bvec[bb * 32 + t] = sb;
        }
    } else {
        // c0 = bq . bk
        red[t] = bq[t] * bk[t] + bq[t + 256] * bk[t + 256];
        __syncthreads();
        for (int off = 128; off > 0; off >>= 1) {
            if (t < off) red[t] += red[t + off];
            __syncthreads();
        }
        if (t == 0) *c0p = red[0];
    }
}

// ============ K2: U-tile GEMM fused with band-diagonal dots ============
// U = ctx_bf @ M_bf^T (never materialized). tile 64(M) x 128(N), BK=32, grid 512.
// Partials (per bn col-slice): PA[r][bn]=U_r·ctx_{r-1}, PB[r][bn]=U_r·ctx_{r+1},
//                              AL[r][bn]=avec·ctx_r,    BE[r][bn]=bvec·ctx_r
__global__ __launch_bounds__(256) void ugemm_fused(const __bf16* __restrict__ A,
                                                   const __bf16* __restrict__ Bt,
                                                   const float* __restrict__ ctxf,
                                                   const float* __restrict__ avec,
                                                   const float* __restrict__ bvec,
                                                   float* __restrict__ PA,
                                                   float* __restrict__ PB,
                                                   float* __restrict__ AL,
                                                   float* __restrict__ BE) {
    __shared__ alignas(16) __bf16 As[64 * 32];
    __shared__ alignas(16) __bf16 Bs[128 * 32];
    __shared__ float Utile[64][132];     // +4 pad: write conflicts 2-way (free)
    const int tid  = threadIdx.x;
    const int lane = tid & 63;
    const int wave = tid >> 6;
    const int wr = wave >> 1, wc = wave & 1;
    const int bm = blockIdx.x >> 2, bn = blockIdx.x & 3;

    f32x4 acc[2][4] = {};
    const int koff = (lane >> 4) * 8;
    const int frow = lane & 15;
    const int row = tid >> 2, kc = (tid & 3) * 8;

    for (int kt = 0; kt < 512; kt += 32) {
        gload_lds16(A + (size_t)(bm * 64 + row) * 512 + kt + kc,
                    (void*)(As + (size_t)wave * 64 * 8));
        #pragma unroll
        for (int ld = 0; ld < 2; ++ld) {
            const int brow = (ld * 256 + tid) >> 2;
            gload_lds16(Bt + (size_t)(bn * 128 + brow) * 512 + kt + kc,
                        (void*)(Bs + (size_t)(ld * 256 + wave * 64) * 8));
        }
        __syncthreads();
        bf16x8 av[2], bv[4];
        #pragma unroll
        for (int m = 0; m < 2; ++m)
            av[m] = *(const bf16x8*)(As + (wr * 32 + m * 16 + frow) * 32 + koff);
        #pragma unroll
        for (int n = 0; n < 4; ++n)
            bv[n] = *(const bf16x8*)(Bs + (wc * 64 + n * 16 + frow) * 32 + koff);
        #pragma unroll
        for (int m = 0; m < 2; ++m)
            #pragma unroll
            for (int n = 0; n < 4; ++n)
                acc[m][n] = __builtin_amdgcn_mfma_f32_16x16x32_bf16(av[m], bv[n], acc[m][n], 0, 0, 0);
        __syncthreads();
    }

    // stage U-tile to LDS
    #pragma unroll
    for (int m = 0; m < 2; ++m) {
        const int rl = wr * 32 + m * 16 + (lane >> 4) * 4;
        #pragma unroll
        for (int n = 0; n < 4; ++n) {
            const int cl = wc * 64 + n * 16 + frow;
            #pragma unroll
            for (int rg = 0; rg < 4; ++rg)
                Utile[rl + rg][cl] = acc[m][n][rg];
        }
    }
    __syncthreads();

    // per-wave: 16 rows; dot U-row with f32 ctx neighbor rows (coalesced float2)
    const int cb = bn * 128;
    const float2 av2 = *(const float2*)(avec + cb + 2 * lane);
    const float2 bv2 = *(const float2*)(bvec + cb + 2 * lane);
    for (int rr = 0; rr < 16; ++rr) {
        const int rloc = wave * 16 + rr;
        const int gr   = bm * 64 + rloc;
        const int grp  = (gr + 1 < MROWS) ? gr + 1 : gr;   // clamped; unused at edges
        const int grm  = (gr > 0) ? gr - 1 : gr;
        const float2 u  = *(const float2*)&Utile[rloc][2 * lane];
        const float2 cp = *(const float2*)(ctxf + (size_t)grp * DD + cb + 2 * lane);
        const float2 cm = *(const float2*)(ctxf + (size_t)grm * DD + cb + 2 * lane);
        const float2 co = *(const float2*)(ctxf + (size_t)gr  * DD + cb + 2 * lane);
        float dA  = u.x * cm.x + u.y * cm.y;
        float dB  = u.x * cp.x + u.y * cp.y;
        float dAl = av2.x * co.x + av2.y * co.y;
        float dBe = bv2.x * co.x + bv2.y * co.y;
        #pragma unroll
        for (int off = 32; off > 0; off >>= 1) {
            dA  += __shfl_xor(dA,  off);
            dB  += __shfl_xor(dB,  off);
            dAl += __shfl_xor(dAl, off);
            dBe += __shfl_xor(dBe, off);
        }
        if (lane == 0) {
            PA[gr * 4 + bn] = dA;
            PB[gr * 4 + bn] = dB;
            AL[gr * 4 + bn] = dAl;
            BE[gr * 4 + bn] = dBe;
        }
    }
}

// ============ K3: softmax + per-batch scan (8 blocks x 1024) ============
__global__ __launch_bounds__(1024) void scan_fused(const float* __restrict__ PA,
                                                   const float* __restrict__ PB,
                                                   const float* __restrict__ AL,
                                                   const float* __restrict__ BE,
                                                   const float* __restrict__ c0p,
                                                   const int* __restrict__ eos,
                                                   const float* __restrict__ prior,
                                                   float* __restrict__ pp,
                                                   float* __restrict__ pm,
                                                   float* __restrict__ uniV,
                                                   float* __restrict__ Cbuf) {
    __shared__ float shBe[1024];
    __shared__ float shPm[1024];
    __shared__ float wsum[16];
    const int b = blockIdx.x, s = threadIdx.x;
    const int r = b * SS + s;
    const bool hasP = (s < SS - 1), hasM = (s > 0);

    f32x4 a4 = *(const f32x4*)(AL + r * 4);
    f32x4 e4 = *(const f32x4*)(BE + r * 4);
    const float al  = a4[0] + a4[1] + a4[2] + a4[3];
    const float beS = e4[0] + e4[1] + e4[2] + e4[3];
    float sp = 0.f, sm = 0.f;
    if (hasP) { f32x4 p4 = *(const f32x4*)(PA + (size_t)(r + 1) * 4); sp = p4[0] + p4[1] + p4[2] + p4[3]; }
    if (hasM) { f32x4 m4 = *(const f32x4*)(PB + (size_t)(r - 1) * 4); sm = m4[0] + m4[1] + m4[2] + m4[3]; }

    shBe[s] = beS;
    __syncthreads();
    const float c0 = *c0p;
    const float scp = (sp + al + (hasP ? shBe[s + 1] : 0.f) + c0) * (1.f / (float)DD);
    const float scm = (sm + al + (hasM ? shBe[s - 1] : 0.f) + c0) * (1.f / (float)DD);

    const bool vp = hasP && (eos[(size_t)b * SS * SS + (size_t)s * SS + (s + 1)] != 0);
    const bool vm = hasM && (eos[(size_t)b * SS * SS + (size_t)s * SS + (s - 1)] != 0);

    float opp, opm, ouni;
    if (!vp && !vm) {
        opp = INV_S; opm = INV_S; ouni = INV_S;
    } else {
        float mx = -3.0e38f;
        if (vp) mx = scp;
        if (vm) mx = fmaxf(mx, scm);
        float ep = vp ? __expf(scp - mx) : 0.f;
        float em = vm ? __expf(scm - mx) : 0.f;
        float inv = 1.f / (ep + em);
        opp = ep * inv; opm = em * inv; ouni = 0.f;
    }
    pp[r] = opp; pm[r] = opm; uniV[r] = ouni;

    shPm[s] = opm;
    __syncthreads();
    float Lj = 0.f;
    if (hasP) {
        float pr = prior[(size_t)b * SS * SS + (size_t)s * SS + (s + 1)];
        float prod = opp * shPm[s + 1];
        float na = pr + (1.f - pr) * sqrtf(prod + NEG_EPS);
        Lj = __logf(na + NEG_EPS);
    }

    // shfl-based inclusive scan over 1024 = 16 waves x 64
    float v = Lj;
    #pragma unroll
    for (int off = 1; off < 64; off <<= 1) {
        float t = __shfl_up(v, off);
        if ((s & 63) >= off) v += t;
    }
    if ((s & 63) == 63) wsum[s >> 6] = v;
    __syncthreads();
    if (s < 64) {
        float w = (s < 16) ? wsum[s] : 0.f;
        #pragma unroll
        for (int off = 1; off < 16; off <<= 1) {
            float t = __shfl_up(w, off);
            if (s >= off) w += t;
        }
        if (s < 16) wsum[s] = w;      // inclusive wave sums
    }
    __syncthreads();
    const float base = (s >= 64) ? wsum[(s >> 6) - 1] : 0.f;
    Cbuf[r] = base + v - Lj;          // exclusive prefix
}

// ============ K4: dense fill of both outputs ============
__global__ __launch_bounds__(256) void fill_kernel(const float* __restrict__ prior,
                                                   const float* __restrict__ pp,
                                                   const float* __restrict__ pm,
                                                   const float* __restrict__ uniV,
                                                   const float* __restrict__ Cbuf,
                                                   float* __restrict__ gout,
                                                   float* __restrict__ naout) {
    const int r = blockIdx.x;
    const int b = r >> 10, q = r & 1023;
    const int k0 = threadIdx.x * 4;
    const size_t rowoff = (size_t)r * SS;

    f32x4 pr4 = *(const f32x4*)(prior + rowoff + k0);
    f32x4 uk4 = *(const f32x4*)(uniV + (b << 10) + k0);
    f32x4 C4  = *(const f32x4*)(Cbuf + (b << 10) + k0);
    float uniq = uniV[r];
    float ppq  = pp[r];
    float pmq  = pm[r];
    float Cq   = Cbuf[r];
    float ppp  = (q > 0)      ? pp[r - 1] : 0.f;
    float pmn  = (q < SS - 1) ? pm[r + 1] : 0.f;

    f32x4 g4, na4;
    #pragma unroll
    for (int j = 0; j < 4; ++j) {
        int k = k0 + j;
        float pr = pr4[j];
        float Aqk = (k == q - 1) ? pmq : ((k == q + 1) ? ppq : uniq);
        float Akq = (k == q - 1) ? ppp : ((k == q + 1) ? pmn : uk4[j]);
        float na = pr + (1.f - pr) * sqrtf(Aqk * Akq + NEG_EPS);
        float g;
        if (k == q) {
            g = na;
        } else {
            float dd = (k > q) ? (C4[j] - Cq) : (Cq - C4[j]);
            g = __expf(dd) + NEG_EPS;
        }
        na4[j] = na;
        g4[j]  = g;
    }
    *(f32x4*)(gout + rowoff + k0)  = g4;
    *(f32x4*)(naout + rowoff + k0) = na4;
}

extern "C" void kernel_launch(void* const* d_in, const int* in_sizes, int n_in,
                              void* d_out, int out_size, void* d_ws, size_t ws_size,
                              hipStream_t stream) {
    const float* ctx   = (const float*)d_in[0];
    const int*   eos   = (const int*)d_in[1];
    const float* prior = (const float*)d_in[2];
    const float* Wk    = (const float*)d_in[3];
    const float* bk    = (const float*)d_in[4];
    const float* Wq    = (const float*)d_in[5];
    const float* bq    = (const float*)d_in[6];

    float* gout  = (float*)d_out;
    float* naout = gout + (size_t)BB * SS * SS;

    char* ws = (char*)d_ws;
    __bf16* ctx_bf = (__bf16*)ws;                            // 8 MiB
    __bf16* m_bf   = (__bf16*)(ws + (8u << 20));             // 512 KiB
    float*  PA     = (float*)(ws + (9u << 20));              // 128 KiB each
    float*  PB     = PA + MROWS * 4;
    float*  AL     = PB + MROWS * 4;
    float*  BE     = AL + MROWS * 4;
    float*  avec   = BE + MROWS * 4;                         // 2 KiB
    float*  bvec   = avec + 512;
    float*  c0p    = bvec + 512;
    float*  ppb    = (float*)(ws + (10u << 20));             // 32 KiB each
    float*  pmb    = ppb + MROWS;
    float*  uniV   = pmb + MROWS;
    float*  Cbuf   = uniV + MROWS;

    prep_all<<<2321, 256, 0, stream>>>(ctx, Wq, Wk, bq, bk, ctx_bf, m_bf, avec, bvec, c0p);
    ugemm_fused<<<512, 256, 0, stream>>>(ctx_bf, m_bf, ctx, avec, bvec, PA, PB, AL, BE);
    scan_fused<<<BB, 1024, 0, stream>>>(PA, PB, AL, BE, c0p, eos, prior, ppb, pmb, uniV, Cbuf);
    fill_kernel<<<MROWS, 256, 0, stream>>>(prior, ppb, pmb, uniV, Cbuf, gout, naout);
}

// Round 5
// 176.401 us; speedup vs baseline: 1.2667x; 1.2667x over previous
//
#include <hip/hip_runtime.h>
#include <hip/hip_bf16.h>
#include <stdint.h>

// Problem constants
#define BB 8
#define SS 1024
#define DD 512
#define MROWS (BB*SS)        // 8192
#define NEG_EPS 1e-9f
#define INV_S (1.0f/1024.0f)

typedef __attribute__((ext_vector_type(8))) __bf16 bf16x8;
typedef __attribute__((ext_vector_type(4))) __bf16 bf16x4;
typedef __attribute__((ext_vector_type(4))) float f32x4;

__device__ __forceinline__ void gload_lds16(const void* g, void* l) {
    __builtin_amdgcn_global_load_lds(
        (const __attribute__((address_space(1))) void*)g,
        (__attribute__((address_space(3))) void*)l,
        16, 0, 0);
}

// ============ K1: ctx->bf16 + transpose-convert Wq/Wk -> WqT/WkT (bf16) + bias ============
// grid: [0,2048) ctx convert, [2048,2304) Wq transpose, [2304,2560) Wk transpose,
//       [2560,2576) bias vecs, 2576 c0
__global__ __launch_bounds__(256) void prep_all(const float* __restrict__ ctx,
                                                const float* __restrict__ Wq,
                                                const float* __restrict__ Wk,
                                                const float* __restrict__ bq,
                                                const float* __restrict__ bk,
                                                __bf16* __restrict__ ctx_bf,
                                                __bf16* __restrict__ WqT,
                                                __bf16* __restrict__ WkT,
                                                float* __restrict__ avec,
                                                float* __restrict__ bvec,
                                                float* __restrict__ c0p) {
    __shared__ float sT[32][33];
    __shared__ float red[256];
    __shared__ float sA[8][32];
    __shared__ float sB[8][32];
    const int blk = blockIdx.x;
    const int t = threadIdx.x;

    if (blk < 2048) {
        int i = (blk * 256 + t) * 4;
        const int stride = 2048 * 256 * 4;
        for (; i < MROWS * DD; i += stride) {
            f32x4 v = *(const f32x4*)(ctx + i);
            bf16x4 o;
            o[0] = (__bf16)v[0]; o[1] = (__bf16)v[1];
            o[2] = (__bf16)v[2]; o[3] = (__bf16)v[3];
            *(bf16x4*)(ctx_bf + i) = o;
        }
    } else if (blk < 2560) {
        // transpose-convert one 32x32 tile: out[i][e] = W[e][i]
        const int tt = blk - 2048;
        const bool isK = tt >= 256;
        const float* W = isK ? Wk : Wq;
        __bf16* out = isK ? WkT : WqT;
        const int ti = isK ? tt - 256 : tt;
        const int e0 = (ti >> 4) * 32, i0 = (ti & 15) * 32;
        const int r = t >> 3, c4 = (t & 7) * 4;
        f32x4 v = *(const f32x4*)(W + (size_t)(e0 + r) * 512 + i0 + c4);
        sT[r][c4] = v[0]; sT[r][c4 + 1] = v[1];
        sT[r][c4 + 2] = v[2]; sT[r][c4 + 3] = v[3];
        __syncthreads();
        bf16x4 o;
        o[0] = (__bf16)sT[c4][r];     o[1] = (__bf16)sT[c4 + 1][r];
        o[2] = (__bf16)sT[c4 + 2][r]; o[3] = (__bf16)sT[c4 + 3][r];
        *(bf16x4*)(out + (size_t)(i0 + r) * 512 + e0 + c4) = o;
    } else if (blk < 2576) {
        // a = Wq^T bk, b = Wk^T bq — 16 blocks x 32 columns, 8 e-groups each
        const int bb = blk - 2560;
        const int d  = (t & 31) + bb * 32;
        const int eg = t >> 5;
        float a = 0.f, bv = 0.f;
        for (int e = eg * 64; e < eg * 64 + 64; ++e) {
            a  += Wq[(size_t)e * 512 + d] * bk[e];
            bv += Wk[(size_t)e * 512 + d] * bq[e];
        }
        sA[eg][t & 31] = a; sB[eg][t & 31] = bv;
        __syncthreads();
        if (t < 32) {
            float sa = 0.f, sb = 0.f;
            #pragma unroll
            for (int g = 0; g < 8; ++g) { sa += sA[g][t]; sb += sB[g][t]; }
            avec[bb * 32 + t] = sa; bvec[bb * 32 + t] = sb;
        }
    } else {
        // c0 = bq . bk
        red[t] = bq[t] * bk[t] + bq[t + 256] * bk[t + 256];
        __syncthreads();
        for (int off = 128; off > 0; off >>= 1) {
            if (t < off) red[t] += red[t + off];
            __syncthreads();
        }
        if (t == 0) *c0p = red[0];
    }
}

// ============ K2: M = WqT @ WkT^T (MFMA), M[i][j] = sum_e Wq[e,i]Wk[e,j] ============
// tile 64(M) x 128(N), BK=32, grid = 8*4 = 32 blocks
__global__ __launch_bounds__(256) void m_gemm(const __bf16* __restrict__ A,
                                              const __bf16* __restrict__ Bt,
                                              __bf16* __restrict__ Mout) {
    __shared__ alignas(16) __bf16 As[64 * 32];
    __shared__ alignas(16) __bf16 Bs[128 * 32];
    const int tid  = threadIdx.x;
    const int lane = tid & 63;
    const int wave = tid >> 6;
    const int wr = wave >> 1, wc = wave & 1;
    const int bm = blockIdx.x >> 2, bn = blockIdx.x & 3;

    f32x4 acc[2][4] = {};
    const int koff = (lane >> 4) * 8;
    const int frow = lane & 15;
    const int row = tid >> 2, kc = (tid & 3) * 8;

    for (int kt = 0; kt < 512; kt += 32) {
        gload_lds16(A + (size_t)(bm * 64 + row) * 512 + kt + kc,
                    (void*)(As + (size_t)wave * 64 * 8));
        #pragma unroll
        for (int ld = 0; ld < 2; ++ld) {
            const int brow = (ld * 256 + tid) >> 2;
            gload_lds16(Bt + (size_t)(bn * 128 + brow) * 512 + kt + kc,
                        (void*)(Bs + (size_t)(ld * 256 + wave * 64) * 8));
        }
        __syncthreads();
        bf16x8 av[2], bv[4];
        #pragma unroll
        for (int m = 0; m < 2; ++m)
            av[m] = *(const bf16x8*)(As + (wr * 32 + m * 16 + frow) * 32 + koff);
        #pragma unroll
        for (int n = 0; n < 4; ++n)
            bv[n] = *(const bf16x8*)(Bs + (wc * 64 + n * 16 + frow) * 32 + koff);
        #pragma unroll
        for (int m = 0; m < 2; ++m)
            #pragma unroll
            for (int n = 0; n < 4; ++n)
                acc[m][n] = __builtin_amdgcn_mfma_f32_16x16x32_bf16(av[m], bv[n], acc[m][n], 0, 0, 0);
        __syncthreads();
    }

    #pragma unroll
    for (int m = 0; m < 2; ++m) {
        const int r0 = bm * 64 + wr * 32 + m * 16 + (lane >> 4) * 4;
        #pragma unroll
        for (int n = 0; n < 4; ++n) {
            const int col = bn * 128 + wc * 64 + n * 16 + frow;
            #pragma unroll
            for (int rg = 0; rg < 4; ++rg)
                Mout[(size_t)(r0 + rg) * 512 + col] = (__bf16)acc[m][n][rg];
        }
    }
}

// ============ K3: U-tile GEMM fused with band-diagonal dots ============
// U = ctx_bf @ M^T (never materialized). tile 64(M) x 128(N), BK=32, grid 512.
// XCD-aware decode: 4 bn-blocks sharing an A-tile land on the same XCD.
__global__ __launch_bounds__(256) void ugemm_fused(const __bf16* __restrict__ A,
                                                   const __bf16* __restrict__ Bt,
                                                   const float* __restrict__ ctxf,
                                                   const float* __restrict__ avec,
                                                   const float* __restrict__ bvec,
                                                   float* __restrict__ PA,
                                                   float* __restrict__ PB,
                                                   float* __restrict__ AL,
                                                   float* __restrict__ BE) {
    __shared__ alignas(16) __bf16 As[64 * 32];
    __shared__ alignas(16) __bf16 Bs[128 * 32];
    __shared__ float Utile[64][132];     // +4 pad: write conflicts 2-way (free)
    const int tid  = threadIdx.x;
    const int lane = tid & 63;
    const int wave = tid >> 6;
    const int wr = wave >> 1, wc = wave & 1;
    const int local = blockIdx.x >> 3;
    const int xcd   = blockIdx.x & 7;
    const int bm = xcd * 16 + (local >> 2);   // 0..127
    const int bn = local & 3;

    f32x4 acc[2][4] = {};
    const int koff = (lane >> 4) * 8;
    const int frow = lane & 15;
    const int row = tid >> 2, kc = (tid & 3) * 8;

    for (int kt = 0; kt < 512; kt += 32) {
        gload_lds16(A + (size_t)(bm * 64 + row) * 512 + kt + kc,
                    (void*)(As + (size_t)wave * 64 * 8));
        #pragma unroll
        for (int ld = 0; ld < 2; ++ld) {
            const int brow = (ld * 256 + tid) >> 2;
            gload_lds16(Bt + (size_t)(bn * 128 + brow) * 512 + kt + kc,
                        (void*)(Bs + (size_t)(ld * 256 + wave * 64) * 8));
        }
        __syncthreads();
        bf16x8 av[2], bv[4];
        #pragma unroll
        for (int m = 0; m < 2; ++m)
            av[m] = *(const bf16x8*)(As + (wr * 32 + m * 16 + frow) * 32 + koff);
        #pragma unroll
        for (int n = 0; n < 4; ++n)
            bv[n] = *(const bf16x8*)(Bs + (wc * 64 + n * 16 + frow) * 32 + koff);
        #pragma unroll
        for (int m = 0; m < 2; ++m)
            #pragma unroll
            for (int n = 0; n < 4; ++n)
                acc[m][n] = __builtin_amdgcn_mfma_f32_16x16x32_bf16(av[m], bv[n], acc[m][n], 0, 0, 0);
        __syncthreads();
    }

    // stage U-tile to LDS
    #pragma unroll
    for (int m = 0; m < 2; ++m) {
        const int rl = wr * 32 + m * 16 + (lane >> 4) * 4;
        #pragma unroll
        for (int n = 0; n < 4; ++n) {
            const int cl = wc * 64 + n * 16 + frow;
            #pragma unroll
            for (int rg = 0; rg < 4; ++rg)
                Utile[rl + rg][cl] = acc[m][n][rg];
        }
    }
    __syncthreads();

    // per-wave: 16 rows; dot U-row with f32 ctx neighbor rows (coalesced float2)
    const int cb = bn * 128;
    const float2 av2 = *(const float2*)(avec + cb + 2 * lane);
    const float2 bv2 = *(const float2*)(bvec + cb + 2 * lane);
    for (int rr = 0; rr < 16; ++rr) {
        const int rloc = wave * 16 + rr;
        const int gr   = bm * 64 + rloc;
        const int grp  = (gr + 1 < MROWS) ? gr + 1 : gr;   // clamped; unused at edges
        const int grm  = (gr > 0) ? gr - 1 : gr;
        const float2 u  = *(const float2*)&Utile[rloc][2 * lane];
        const float2 cp = *(const float2*)(ctxf + (size_t)grp * DD + cb + 2 * lane);
        const float2 cm = *(const float2*)(ctxf + (size_t)grm * DD + cb + 2 * lane);
        const float2 co = *(const float2*)(ctxf + (size_t)gr  * DD + cb + 2 * lane);
        float dA  = u.x * cm.x + u.y * cm.y;
        float dB  = u.x * cp.x + u.y * cp.y;
        float dAl = av2.x * co.x + av2.y * co.y;
        float dBe = bv2.x * co.x + bv2.y * co.y;
        #pragma unroll
        for (int off = 32; off > 0; off >>= 1) {
            dA  += __shfl_xor(dA,  off);
            dB  += __shfl_xor(dB,  off);
            dAl += __shfl_xor(dAl, off);
            dBe += __shfl_xor(dBe, off);
        }
        if (lane == 0) {
            PA[gr * 4 + bn] = dA;
            PB[gr * 4 + bn] = dB;
            AL[gr * 4 + bn] = dAl;
            BE[gr * 4 + bn] = dBe;
        }
    }
}

// ============ K4: softmax + per-batch scan (8 blocks x 1024) ============
__global__ __launch_bounds__(1024) void scan_fused(const float* __restrict__ PA,
                                                   const float* __restrict__ PB,
                                                   const float* __restrict__ AL,
                                                   const float* __restrict__ BE,
                                                   const float* __restrict__ c0p,
                                                   const int* __restrict__ eos,
                                                   const float* __restrict__ prior,
                                                   float* __restrict__ pp,
                                                   float* __restrict__ pm,
                                                   float* __restrict__ uniV,
                                                   float* __restrict__ Cbuf) {
    __shared__ float shBe[1024];
    __shared__ float shPm[1024];
    __shared__ float wsum[16];
    const int b = blockIdx.x, s = threadIdx.x;
    const int r = b * SS + s;
    const bool hasP = (s < SS - 1), hasM = (s > 0);

    f32x4 a4 = *(const f32x4*)(AL + r * 4);
    f32x4 e4 = *(const f32x4*)(BE + r * 4);
    const float al  = a4[0] + a4[1] + a4[2] + a4[3];
    const float beS = e4[0] + e4[1] + e4[2] + e4[3];
    float sp = 0.f, sm = 0.f;
    if (hasP) { f32x4 p4 = *(const f32x4*)(PA + (size_t)(r + 1) * 4); sp = p4[0] + p4[1] + p4[2] + p4[3]; }
    if (hasM) { f32x4 m4 = *(const f32x4*)(PB + (size_t)(r - 1) * 4); sm = m4[0] + m4[1] + m4[2] + m4[3]; }

    shBe[s] = beS;
    __syncthreads();
    const float c0 = *c0p;
    const float scp = (sp + al + (hasP ? shBe[s + 1] : 0.f) + c0) * (1.f / (float)DD);
    const float scm = (sm + al + (hasM ? shBe[s - 1] : 0.f) + c0) * (1.f / (float)DD);

    const bool vp = hasP && (eos[(size_t)b * SS * SS + (size_t)s * SS + (s + 1)] != 0);
    const bool vm = hasM && (eos[(size_t)b * SS * SS + (size_t)s * SS + (s - 1)] != 0);

    float opp, opm, ouni;
    if (!vp && !vm) {
        opp = INV_S; opm = INV_S; ouni = INV_S;
    } else {
        float mx = -3.0e38f;
        if (vp) mx = scp;
        if (vm) mx = fmaxf(mx, scm);
        float ep = vp ? __expf(scp - mx) : 0.f;
        float em = vm ? __expf(scm - mx) : 0.f;
        float inv = 1.f / (ep + em);
        opp = ep * inv; opm = em * inv; ouni = 0.f;
    }
    pp[r] = opp; pm[r] = opm; uniV[r] = ouni;

    shPm[s] = opm;
    __syncthreads();
    float Lj = 0.f;
    if (hasP) {
        float pr = prior[(size_t)b * SS * SS + (size_t)s * SS + (s + 1)];
        float prod = opp * shPm[s + 1];
        float na = pr + (1.f - pr) * sqrtf(prod + NEG_EPS);
        Lj = __logf(na + NEG_EPS);
    }

    // shfl-based inclusive scan over 1024 = 16 waves x 64
    float v = Lj;
    #pragma unroll
    for (int off = 1; off < 64; off <<= 1) {
        float t = __shfl_up(v, off);
        if ((s & 63) >= off) v += t;
    }
    if ((s & 63) == 63) wsum[s >> 6] = v;
    __syncthreads();
    if (s < 64) {
        float w = (s < 16) ? wsum[s] : 0.f;
        #pragma unroll
        for (int off = 1; off < 16; off <<= 1) {
            float t = __shfl_up(w, off);
            if (s >= off) w += t;
        }
        if (s < 16) wsum[s] = w;      // inclusive wave sums
    }
    __syncthreads();
    const float base = (s >= 64) ? wsum[(s >> 6) - 1] : 0.f;
    Cbuf[r] = base + v - Lj;          // exclusive prefix
}

// ============ K5: dense fill of both outputs ============
__global__ __launch_bounds__(256) void fill_kernel(const float* __restrict__ prior,
                                                   const float* __restrict__ pp,
                                                   const float* __restrict__ pm,
                                                   const float* __restrict__ uniV,
                                                   const float* __restrict__ Cbuf,
                                                   float* __restrict__ gout,
                                                   float* __restrict__ naout) {
    const int r = blockIdx.x;
    const int b = r >> 10, q = r & 1023;
    const int k0 = threadIdx.x * 4;
    const size_t rowoff = (size_t)r * SS;

    f32x4 pr4 = *(const f32x4*)(prior + rowoff + k0);
    f32x4 uk4 = *(const f32x4*)(uniV + (b << 10) + k0);
    f32x4 C4  = *(const f32x4*)(Cbuf + (b << 10) + k0);
    float uniq = uniV[r];
    float ppq  = pp[r];
    float pmq  = pm[r];
    float Cq   = Cbuf[r];
    float ppp  = (q > 0)      ? pp[r - 1] : 0.f;
    float pmn  = (q < SS - 1) ? pm[r + 1] : 0.f;

    f32x4 g4, na4;
    #pragma unroll
    for (int j = 0; j < 4; ++j) {
        int k = k0 + j;
        float pr = pr4[j];
        float Aqk = (k == q - 1) ? pmq : ((k == q + 1) ? ppq : uniq);
        float Akq = (k == q - 1) ? ppp : ((k == q + 1) ? pmn : uk4[j]);
        float na = pr + (1.f - pr) * sqrtf(Aqk * Akq + NEG_EPS);
        float g;
        if (k == q) {
            g = na;
        } else {
            float dd = (k > q) ? (C4[j] - Cq) : (Cq - C4[j]);
            g = __expf(dd) + NEG_EPS;
        }
        na4[j] = na;
        g4[j]  = g;
    }
    *(f32x4*)(gout + rowoff + k0)  = g4;
    *(f32x4*)(naout + rowoff + k0) = na4;
}

extern "C" void kernel_launch(void* const* d_in, const int* in_sizes, int n_in,
                              void* d_out, int out_size, void* d_ws, size_t ws_size,
                              hipStream_t stream) {
    const float* ctx   = (const float*)d_in[0];
    const int*   eos   = (const int*)d_in[1];
    const float* prior = (const float*)d_in[2];
    const float* Wk    = (const float*)d_in[3];
    const float* bk    = (const float*)d_in[4];
    const float* Wq    = (const float*)d_in[5];
    const float* bq    = (const float*)d_in[6];

    float* gout  = (float*)d_out;
    float* naout = gout + (size_t)BB * SS * SS;

    char* ws = (char*)d_ws;
    __bf16* ctx_bf = (__bf16*)ws;                            // 8 MiB
    __bf16* WqT    = (__bf16*)(ws + (8u  << 20));            // 512 KiB
    __bf16* WkT    = (__bf16*)(ws + (8u  << 20) + (512u << 10));
    __bf16* m_bf   = (__bf16*)(ws + (9u  << 20));            // 512 KiB
    float*  PA     = (float*)(ws + (10u << 20));             // 128 KiB each
    float*  PB     = PA + MROWS * 4;
    float*  AL     = PB + MROWS * 4;
    float*  BE     = AL + MROWS * 4;
    float*  avec   = BE + MROWS * 4;                         // 2 KiB
    float*  bvec   = avec + 512;
    float*  c0p    = bvec + 512;
    float*  ppb    = (float*)(ws + (11u << 20));             // 32 KiB each
    float*  pmb    = ppb + MROWS;
    float*  uniV   = pmb + MROWS;
    float*  Cbuf   = uniV + MROWS;

    prep_all<<<2577, 256, 0, stream>>>(ctx, Wq, Wk, bq, bk, ctx_bf, WqT, WkT, avec, bvec, c0p);
    m_gemm<<<32, 256, 0, stream>>>(WqT, WkT, m_bf);
    ugemm_fused<<<512, 256, 0, stream>>>(ctx_bf, m_bf, ctx, avec, bvec, PA, PB, AL, BE);
    scan_fused<<<BB, 1024, 0, stream>>>(PA, PB, AL, BE, c0p, eos, prior, ppb, pmb, uniV, Cbuf);
    fill_kernel<<<MROWS, 256, 0, stream>>>(prior, ppb, pmb, uniV, Cbuf, gout, naout);
}